// Round 6
// baseline (248.184 us; speedup 1.0000x reference)
//
#include <hip/hip_runtime.h>
#include <math.h>

#define B_ 4
#define C_ 128
#define N_ 4096
#define NSPLIT 4
#define MT 64
#define VLD 72    // Vs row stride (shorts): 64+8, 16B-aligned
#define PLD 72
#define HLD 136   // gnqkv h-tile row stride (shorts)

typedef float floatx4 __attribute__((ext_vector_type(4)));
typedef short bf16x8 __attribute__((ext_vector_type(8)));
typedef short bf16x4 __attribute__((ext_vector_type(4)));

__device__ __forceinline__ ushort f2bf(float f) {  // RNE
  unsigned u = __float_as_uint(f);
  return (ushort)((u + 0x7FFF + ((u >> 16) & 1)) >> 16);
}
__device__ __forceinline__ float bf2f(ushort u) {
  return __uint_as_float(((unsigned)u) << 16);
}
// pack two floats -> (hi16(a)<<16)|hi16(b), round-half-up
__device__ __forceinline__ unsigned pkbf(float a, float b) {
  return __builtin_amdgcn_perm(__float_as_uint(a) + 0x8000u,
                               __float_as_uint(b) + 0x8000u, 0x07060302u);
}

// ---------------- convert 4 weight matrices fp32 -> bf16 ----------------
__global__ __launch_bounds__(256) void wcvt_kernel(
    const float* __restrict__ wq, const float* __restrict__ wk,
    const float* __restrict__ wv, const float* __restrict__ wp,
    ushort* __restrict__ wB) {
  int i = blockIdx.x * 256 + threadIdx.x;   // grid 256 -> 65536
  int m = i >> 14, j = i & 16383;
  const float* src = (m == 0) ? wq : (m == 1) ? wk : (m == 2) ? wv : wp;
  wB[i] = f2bf(src[j]);
}

// ---------------- GN stats, atomic-free: grid 256 = (b, g, part) ----------------
// gstat[0..255] = partial sums, gstat[256..511] = partial sum-of-squares
__global__ __launch_bounds__(256) void gn_stats(
    const float* __restrict__ x, float* __restrict__ gstat) {
  int b = blockIdx.x >> 6, g = (blockIdx.x >> 3) & 7, part = blockIdx.x & 7;
  const float4* xp = (const float4*)(x + (size_t)(b * C_ + g * 16) * N_) + part * 2048;
  float s = 0.f, ss = 0.f;
  for (int i = threadIdx.x; i < 2048; i += 256) {
    float4 v = xp[i];
    s += v.x + v.y + v.z + v.w;
    ss += v.x * v.x + v.y * v.y + v.z * v.z + v.w * v.w;
  }
  #pragma unroll
  for (int o = 32; o > 0; o >>= 1) {
    s += __shfl_down(s, o, 64);
    ss += __shfl_down(ss, o, 64);
  }
  __shared__ float rs[4], rss[4];
  int wid = threadIdx.x >> 6, lane = threadIdx.x & 63;
  if (lane == 0) { rs[wid] = s; rss[wid] = ss; }
  __syncthreads();
  if (threadIdx.x == 0) {
    int slot = (b * 8 + g) * 8 + part;
    gstat[slot]       = rs[0] + rs[1] + rs[2] + rs[3];
    gstat[256 + slot] = rss[0] + rss[1] + rss[2] + rss[3];
  }
}

// ---------------- fused GN-apply + QKV MFMA: grid 512 = (b, 32-n tile) ----------------
__global__ __launch_bounds__(256) void gnqkv_kernel(
    const float* __restrict__ x, const float* __restrict__ gstat,
    const float* __restrict__ scale, const float* __restrict__ bias,
    const ushort* __restrict__ wB,
    const float* __restrict__ bq, const float* __restrict__ bk,
    const float* __restrict__ bv,
    ushort* __restrict__ qT, ushort* __restrict__ kT, ushort* __restrict__ vB) {
  __shared__ __align__(16) ushort hs[32][HLD];   // 8704 B
  __shared__ float sSc[C_], sBi[C_];
  int tid = threadIdx.x;
  int b = blockIdx.x >> 7;
  int n0 = (blockIdx.x & 127) * 32;
  if (tid < 128) {
    int g = tid >> 4;
    float S = 0.f, SS = 0.f;
    #pragma unroll
    for (int p = 0; p < 8; ++p) {
      S  += gstat[(b * 8 + g) * 8 + p];
      SS += gstat[256 + (b * 8 + g) * 8 + p];
    }
    float mu = S * (1.f / 65536.f);
    float var = SS * (1.f / 65536.f) - mu * mu;
    float rstd = rsqrtf(var + 1e-6f);
    float sc = scale[tid] * rstd;
    sSc[tid] = sc;
    sBi[tid] = bias[tid] - mu * sc;
  }
  __syncthreads();
  for (int i = tid; i < 1024; i += 256) {   // 128 c x 8 float4 (32 n)
    int c = i >> 3, n4 = i & 7;
    float4 v = *(const float4*)(x + (size_t)(b * C_ + c) * N_ + n0 + n4 * 4);
    float sc = sSc[c], bi = sBi[c];
    hs[n4 * 4 + 0][c] = f2bf(v.x * sc + bi);
    hs[n4 * 4 + 1][c] = f2bf(v.y * sc + bi);
    hs[n4 * 4 + 2][c] = f2bf(v.z * sc + bi);
    hs[n4 * 4 + 3][c] = f2bf(v.w * sc + bi);
  }
  __syncthreads();
  int lane = tid & 63, w = tid >> 6;
  int col = lane & 15, quad = lane >> 4;
  int nl = (w & 1) * 16 + col;
  int n = n0 + nl;
  int oh = (w >> 1) * 64;
  bf16x8 hf[4];
  #pragma unroll
  for (int kc = 0; kc < 4; ++kc)
    hf[kc] = *(const bf16x8*)&hs[nl][kc * 32 + quad * 8];
  const ushort* Wq = wB;
  const ushort* Wk = wB + 16384;
  const ushort* Wv = wB + 32768;
  const float scl = 0.12751879752224991f;  // 128^-0.5 * log2(e)
  #pragma unroll
  for (int ot = 0; ot < 4; ++ot) {
    int o0 = oh + ot * 16;
    floatx4 aq = (floatx4)0.f, ak = (floatx4)0.f, av = (floatx4)0.f;
    #pragma unroll
    for (int kc = 0; kc < 4; ++kc) {
      int wo = (o0 + col) * C_ + kc * 32 + quad * 8;
      aq = __builtin_amdgcn_mfma_f32_16x16x32_bf16(*(const bf16x8*)&Wq[wo], hf[kc], aq, 0, 0, 0);
      ak = __builtin_amdgcn_mfma_f32_16x16x32_bf16(*(const bf16x8*)&Wk[wo], hf[kc], ak, 0, 0, 0);
      av = __builtin_amdgcn_mfma_f32_16x16x32_bf16(*(const bf16x8*)&Wv[wo], hf[kc], av, 0, 0, 0);
    }
    float4 bqv = *(const float4*)&bq[o0 + quad * 4];
    float4 bkv = *(const float4*)&bk[o0 + quad * 4];
    float4 bvv = *(const float4*)&bv[o0 + quad * 4];
    uint2 qs = { pkbf((aq[1] + bqv.y) * scl, (aq[0] + bqv.x) * scl),
                 pkbf((aq[3] + bqv.w) * scl, (aq[2] + bqv.z) * scl) };
    uint2 ks = { pkbf(ak[1] + bkv.y, ak[0] + bkv.x),
                 pkbf(ak[3] + bkv.w, ak[2] + bkv.z) };
    *(uint2*)(qT + ((size_t)b * N_ + n) * C_ + o0 + quad * 4) = qs;
    *(uint2*)(kT + ((size_t)b * N_ + n) * C_ + o0 + quad * 4) = ks;
    float vv[4] = {av[0] + bvv.x, av[1] + bvv.y, av[2] + bvv.z, av[3] + bvv.w};
    #pragma unroll
    for (int r = 0; r < 4; ++r)
      vB[((size_t)b * C_ + o0 + quad * 4 + r) * N_ + n] = f2bf(vv[r]);
  }
}

// ---------------- MFMA flash attention: P in registers via 16x16x16 MFMA ----------------
// grid 1024: sp=bx&3, qblk=(bx>>2)&63, b=bx>>8.  256 thr = 4 waves x 16 q-rows
__global__ __launch_bounds__(256, 4) void attn_kernel(
    const ushort* __restrict__ qT, const ushort* __restrict__ kT,
    const ushort* __restrict__ vB, ushort* __restrict__ Op,
    float* __restrict__ Mv, float* __restrict__ Lv) {
  __shared__ __align__(16) ushort Vs[C_ * VLD];   // 18432 B
  __shared__ float alphaS[4][16];
#if !__has_builtin(__builtin_amdgcn_mfma_f32_16x16x16bf16_1k)
  __shared__ __align__(16) ushort Ps[64 * PLD];
#endif
  int sp = blockIdx.x & 3;
  int qblk = (blockIdx.x >> 2) & 63;
  int b = blockIdx.x >> 8;
  int n0 = qblk * 64;
  int tid = threadIdx.x, lane = tid & 63, w = tid >> 6;
  int col = lane & 15, quad = lane >> 4;
  const ushort* kTb = kT + (size_t)b * N_ * C_;
  const ushort* vBb = vB + (size_t)b * C_ * N_;

  bf16x8 qf[4];   // B-frags for this wave's 16 q-rows
  #pragma unroll
  for (int kc = 0; kc < 4; ++kc)
    qf[kc] = *(const bf16x8*)(qT + ((size_t)b * N_ + n0 + w * 16 + col) * C_ + kc * 32 + quad * 8);

  floatx4 Oacc[8];
  #pragma unroll
  for (int ct = 0; ct < 8; ++ct) Oacc[ct] = (floatx4)0.f;
  float mrun = -1e30f, lrun = 0.f;

  for (int it = 0; it < 1024 / MT; ++it) {
    int m0 = sp * 1024 + it * MT;
    __syncthreads();                               // prev iter's Vs readers done
    for (int i = tid; i < 1024; i += 256) {        // V tile: 128 c x 64 m
      int c = i >> 3, m8 = i & 7;
      *(uint4*)&Vs[c * VLD + m8 * 8] = *(const uint4*)(vBb + (size_t)c * N_ + m0 + m8 * 8);
    }
    __syncthreads();

    // S^T = K·Q^T per 16-m tile; K A-frags direct from global (L1-shared by 4 waves)
    floatx4 st[4];
    #pragma unroll
    for (int mt = 0; mt < 4; ++mt) {
      bf16x8 kf[4];
      #pragma unroll
      for (int kc = 0; kc < 4; ++kc)
        kf[kc] = *(const bf16x8*)(kTb + (size_t)(m0 + mt * 16 + col) * C_ + kc * 32 + quad * 8);
      floatx4 acc = (floatx4)0.f;
      #pragma unroll
      for (int kc = 0; kc < 4; ++kc)
        acc = __builtin_amdgcn_mfma_f32_16x16x32_bf16(kf[kc], qf[kc], acc, 0, 0, 0);
      st[mt] = acc;
    }
    // online softmax: lane owns q=col; holds m = mt*16 + quad*4 + r
    float mx = st[0][0];
    #pragma unroll
    for (int mt = 0; mt < 4; ++mt)
      #pragma unroll
      for (int r = 0; r < 4; ++r) mx = fmaxf(mx, st[mt][r]);
    mx = fmaxf(mx, __shfl_xor(mx, 16, 64));
    mx = fmaxf(mx, __shfl_xor(mx, 32, 64));
    float mnew = fmaxf(mrun, mx);
    float al = exp2f(mrun - mnew);
    mrun = mnew;
    float p[4][4];
    float lsum = 0.f;
    #pragma unroll
    for (int mt = 0; mt < 4; ++mt) {
      #pragma unroll
      for (int r = 0; r < 4; ++r) {
        p[mt][r] = exp2f(st[mt][r] - mnew);
        lsum += p[mt][r];
      }
    }
    lsum += __shfl_xor(lsum, 16, 64);
    lsum += __shfl_xor(lsum, 32, 64);
    lrun = lrun * al + lsum;
    if (quad == 0) alphaS[w][col] = al;
    // rescale O: lane rows q = quad*4+r
    float ar[4];
    #pragma unroll
    for (int r = 0; r < 4; ++r) ar[r] = alphaS[w][quad * 4 + r];
    #pragma unroll
    for (int ct = 0; ct < 8; ++ct) {
      Oacc[ct][0] *= ar[0]; Oacc[ct][1] *= ar[1];
      Oacc[ct][2] *= ar[2]; Oacc[ct][3] *= ar[3];
    }
#if __has_builtin(__builtin_amdgcn_mfma_f32_16x16x16bf16_1k)
    // P stays in registers: C-layout (m=quad*4+r) == x16 A-operand k-layout
    union PF { unsigned u[2]; bf16x4 s; } pf[4];
    #pragma unroll
    for (int mt = 0; mt < 4; ++mt) {
      pf[mt].u[0] = pkbf(p[mt][1], p[mt][0]);
      pf[mt].u[1] = pkbf(p[mt][3], p[mt][2]);
    }
    #pragma unroll
    for (int ct = 0; ct < 8; ++ct) {
      #pragma unroll
      for (int mt = 0; mt < 4; ++mt) {
        bf16x4 vf = *(const bf16x4*)&Vs[(ct * 16 + col) * VLD + mt * 16 + quad * 4];
        Oacc[ct] = __builtin_amdgcn_mfma_f32_16x16x16bf16_1k(pf[mt].s, vf, Oacc[ct], 0, 0, 0);
      }
    }
#else
    // fallback: P through LDS, x32 PV
    int prow = (w * 16 + col) * PLD;
    #pragma unroll
    for (int mt = 0; mt < 4; ++mt) {
      uint2 pk = { pkbf(p[mt][1], p[mt][0]), pkbf(p[mt][3], p[mt][2]) };
      *(uint2*)&Ps[prow + mt * 16 + quad * 4] = pk;
    }
    bf16x8 pfa, pfb;
    pfa = *(const bf16x8*)&Ps[(w * 16 + col) * PLD + quad * 8];
    pfb = *(const bf16x8*)&Ps[(w * 16 + col) * PLD + 32 + quad * 8];
    #pragma unroll
    for (int ct = 0; ct < 8; ++ct) {
      bf16x8 vf0 = *(const bf16x8*)&Vs[(ct * 16 + col) * VLD + quad * 8];
      bf16x8 vf1 = *(const bf16x8*)&Vs[(ct * 16 + col) * VLD + 32 + quad * 8];
      Oacc[ct] = __builtin_amdgcn_mfma_f32_16x16x32_bf16(pfa, vf0, Oacc[ct], 0, 0, 0);
      Oacc[ct] = __builtin_amdgcn_mfma_f32_16x16x32_bf16(pfb, vf1, Oacc[ct], 0, 0, 0);
    }
#endif
  }
  // epilogue: Op[sp][b][n][c] bf16 (unnormalized) + m,l
  ushort* OpB = Op + (((size_t)sp * B_ + b) * N_ + n0 + w * 16) * C_;
  #pragma unroll
  for (int ct = 0; ct < 8; ++ct)
    #pragma unroll
    for (int r = 0; r < 4; ++r)
      OpB[(size_t)(quad * 4 + r) * C_ + ct * 16 + col] = f2bf(Oacc[ct][r]);
  if (quad == 0) {
    int idx = b * N_ + n0 + w * 16 + col;
    Mv[(size_t)sp * (B_ * N_) + idx] = mrun;
    Lv[(size_t)sp * (B_ * N_) + idx] = lrun;
  }
}

// ---------------- fused merge(4 splits) + proj MFMA + residual ----------------
__global__ __launch_bounds__(256) void mergeproj_kernel(
    const ushort* __restrict__ Op, const float* __restrict__ Mv,
    const float* __restrict__ Lv, const ushort* __restrict__ wpB,
    const float* __restrict__ bp, const float* __restrict__ x,
    float* __restrict__ out) {
  int tid = threadIdx.x, lane = tid & 63, w = tid >> 6;
  int col = lane & 15, quad = lane >> 4;
  int b = blockIdx.x >> 7;
  int n = (blockIdx.x & 127) * 32 + (w & 1) * 16 + col;
  int oh = (w >> 1) * 64;
  int nIdx = b * N_ + n;
  float m[NSPLIT], l[NSPLIT];
  #pragma unroll
  for (int sp = 0; sp < NSPLIT; ++sp) {
    m[sp] = Mv[sp * (B_ * N_) + nIdx];
    l[sp] = Lv[sp * (B_ * N_) + nIdx];
  }
  float M = fmaxf(fmaxf(m[0], m[1]), fmaxf(m[2], m[3]));
  float wg[NSPLIT], den = 0.f;
  #pragma unroll
  for (int sp = 0; sp < NSPLIT; ++sp) { wg[sp] = exp2f(m[sp] - M); den += wg[sp] * l[sp]; }
  float inv = 1.f / den;
  // merged h-row fragments (8 bf16 per kc), built in-register
  bf16x8 hf[4];
  #pragma unroll
  for (int kc = 0; kc < 4; ++kc) {
    float o[8];
    #pragma unroll
    for (int j = 0; j < 8; ++j) o[j] = 0.f;
    #pragma unroll
    for (int sp = 0; sp < NSPLIT; ++sp) {
      uint4 d = *(const uint4*)&Op[((size_t)sp * (B_ * N_) + nIdx) * C_ + kc * 32 + quad * 8];
      unsigned dd[4] = {d.x, d.y, d.z, d.w};
      #pragma unroll
      for (int j = 0; j < 4; ++j) {
        o[j * 2]     += wg[sp] * bf2f((ushort)(dd[j] & 0xFFFF));
        o[j * 2 + 1] += wg[sp] * bf2f((ushort)(dd[j] >> 16));
      }
    }
    union HF { unsigned u[4]; bf16x8 s; } hfu;
    #pragma unroll
    for (int j = 0; j < 4; ++j)
      hfu.u[j] = pkbf(o[j * 2 + 1] * inv, o[j * 2] * inv);
    hf[kc] = hfu.s;
  }
  #pragma unroll
  for (int ot = 0; ot < 4; ++ot) {
    int o0 = oh + ot * 16;
    floatx4 acc = (floatx4)0.f;
    #pragma unroll
    for (int kc = 0; kc < 4; ++kc) {
      int wo = (o0 + col) * C_ + kc * 32 + quad * 8;
      acc = __builtin_amdgcn_mfma_f32_16x16x32_bf16(*(const bf16x8*)&wpB[wo], hf[kc], acc, 0, 0, 0);
    }
    float4 bpv = *(const float4*)&bp[o0 + quad * 4];
    float bb[4] = {bpv.x, bpv.y, bpv.z, bpv.w};
    #pragma unroll
    for (int r = 0; r < 4; ++r) {
      size_t idx = ((size_t)b * C_ + o0 + quad * 4 + r) * N_ + n;
      out[idx] = acc[r] + bb[r] + x[idx];
    }
  }
}

extern "C" void kernel_launch(void* const* d_in, const int* in_sizes, int n_in,
                              void* d_out, int out_size, void* d_ws, size_t ws_size,
                              hipStream_t stream) {
  const float* x        = (const float*)d_in[0];
  const float* gn_scale = (const float*)d_in[1];
  const float* gn_bias  = (const float*)d_in[2];
  const float* wq = (const float*)d_in[3];
  const float* bq = (const float*)d_in[4];
  const float* wk = (const float*)d_in[5];
  const float* bk = (const float*)d_in[6];
  const float* wv = (const float*)d_in[7];
  const float* bv = (const float*)d_in[8];
  const float* wp = (const float*)d_in[9];
  const float* bp = (const float*)d_in[10];
  float* out = (float*)d_out;

  // workspace map (32 MB):
  // [0,256K) Mv | [256K,512K) Lv | [512K,640K) wB (4x32KB bf16) | [640K,+2KB) gstat
  // [4M,8M) qT | [8M,12M) kT | [12M,16M) vB | [16M,32M) Op[4][B][N][C] bf16
  char* ws = (char*)d_ws;
  float*  Mv    = (float*)ws;
  float*  Lv    = (float*)(ws + 262144);
  ushort* wB    = (ushort*)(ws + 524288);
  float*  gstat = (float*)(ws + 655360);
  ushort* qT    = (ushort*)(ws + (4u << 20));
  ushort* kT    = (ushort*)(ws + (8u << 20));
  ushort* vB    = (ushort*)(ws + (12u << 20));
  ushort* Op    = (ushort*)(ws + (16u << 20));
  ushort* wpB   = wB + 49152;

  wcvt_kernel<<<256, 256, 0, stream>>>(wq, wk, wv, wp, wB);
  gn_stats<<<256, 256, 0, stream>>>(x, gstat);
  gnqkv_kernel<<<512, 256, 0, stream>>>(x, gstat, gn_scale, gn_bias, wB, bq, bk, bv, qT, kT, vB);
  attn_kernel<<<1024, 256, 0, stream>>>(qT, kT, vB, Op, Mv, Lv);
  mergeproj_kernel<<<512, 256, 0, stream>>>(Op, Mv, Lv, wpB, bp, x, out);
}

// Round 7
// 179.069 us; speedup vs baseline: 1.3860x; 1.3860x over previous
//
#include <hip/hip_runtime.h>
#include <math.h>

#define B_ 4
#define C_ 128
#define N_ 4096
#define NSPLIT 4
#define MT 32     // keys per iteration
#define PLD 40    // Ps row stride (shorts): 32 + 8 pad
#define HLD 136   // gnqkv h-tile row stride (shorts)

typedef float floatx4 __attribute__((ext_vector_type(4)));
typedef short bf16x8 __attribute__((ext_vector_type(8)));

__device__ __forceinline__ ushort f2bf(float f) {  // RNE
  unsigned u = __float_as_uint(f);
  return (ushort)((u + 0x7FFF + ((u >> 16) & 1)) >> 16);
}
__device__ __forceinline__ float bf2f(ushort u) {
  return __uint_as_float(((unsigned)u) << 16);
}
// pack two floats -> (hi16(a)<<16)|hi16(b), round-half-up
__device__ __forceinline__ unsigned pkbf(float a, float b) {
  return __builtin_amdgcn_perm(__float_as_uint(a) + 0x8000u,
                               __float_as_uint(b) + 0x8000u, 0x07060302u);
}
// async global -> LDS, 16B per lane; LDS dest = uniform base + lane*16
__device__ __forceinline__ void gl2lds16(const ushort* g, ushort* l) {
  __builtin_amdgcn_global_load_lds(
      (const __attribute__((address_space(1))) void*)g,
      (__attribute__((address_space(3))) void*)l, 16, 0, 0);
}

// ---------------- fused: gn_stats (blocks 0..255) + weight cvt (256..511) ----------------
__global__ __launch_bounds__(256) void prep_kernel(
    const float* __restrict__ x, float* __restrict__ gstat,
    const float* __restrict__ wq, const float* __restrict__ wk,
    const float* __restrict__ wv, const float* __restrict__ wp,
    ushort* __restrict__ wB) {
  if (blockIdx.x >= 256) {   // weight convert: 65536 elems
    int i = (blockIdx.x - 256) * 256 + threadIdx.x;
    int m = i >> 14, j = i & 16383;
    const float* src = (m == 0) ? wq : (m == 1) ? wk : (m == 2) ? wv : wp;
    wB[i] = f2bf(src[j]);
    return;
  }
  int b = blockIdx.x >> 6, g = (blockIdx.x >> 3) & 7, part = blockIdx.x & 7;
  const float4* xp = (const float4*)(x + (size_t)(b * C_ + g * 16) * N_) + part * 2048;
  float s = 0.f, ss = 0.f;
  for (int i = threadIdx.x; i < 2048; i += 256) {
    float4 v = xp[i];
    s += v.x + v.y + v.z + v.w;
    ss += v.x * v.x + v.y * v.y + v.z * v.z + v.w * v.w;
  }
  #pragma unroll
  for (int o = 32; o > 0; o >>= 1) {
    s += __shfl_down(s, o, 64);
    ss += __shfl_down(ss, o, 64);
  }
  __shared__ float rs[4], rss[4];
  int wid = threadIdx.x >> 6, lane = threadIdx.x & 63;
  if (lane == 0) { rs[wid] = s; rss[wid] = ss; }
  __syncthreads();
  if (threadIdx.x == 0) {
    int slot = (b * 8 + g) * 8 + part;
    gstat[slot]       = rs[0] + rs[1] + rs[2] + rs[3];
    gstat[256 + slot] = rss[0] + rss[1] + rss[2] + rss[3];
  }
}

// ---------------- fused GN-apply + QKV MFMA: grid 512 = (b, 32-n tile) ----------------
__global__ __launch_bounds__(256) void gnqkv_kernel(
    const float* __restrict__ x, const float* __restrict__ gstat,
    const float* __restrict__ scale, const float* __restrict__ bias,
    const ushort* __restrict__ wB,
    const float* __restrict__ bq, const float* __restrict__ bk,
    const float* __restrict__ bv,
    ushort* __restrict__ qT, ushort* __restrict__ kT, ushort* __restrict__ vB) {
  __shared__ __align__(16) ushort hs[32][HLD];
  __shared__ float sSc[C_], sBi[C_];
  int tid = threadIdx.x;
  int b = blockIdx.x >> 7;
  int n0 = (blockIdx.x & 127) * 32;
  if (tid < 128) {
    int g = tid >> 4;
    float S = 0.f, SS = 0.f;
    #pragma unroll
    for (int p = 0; p < 8; ++p) {
      S  += gstat[(b * 8 + g) * 8 + p];
      SS += gstat[256 + (b * 8 + g) * 8 + p];
    }
    float mu = S * (1.f / 65536.f);
    float var = SS * (1.f / 65536.f) - mu * mu;
    float rstd = rsqrtf(var + 1e-6f);
    float sc = scale[tid] * rstd;
    sSc[tid] = sc;
    sBi[tid] = bias[tid] - mu * sc;
  }
  __syncthreads();
  for (int i = tid; i < 1024; i += 256) {   // 128 c x 8 float4 (32 n)
    int c = i >> 3, n4 = i & 7;
    float4 v = *(const float4*)(x + (size_t)(b * C_ + c) * N_ + n0 + n4 * 4);
    float sc = sSc[c], bi = sBi[c];
    hs[n4 * 4 + 0][c] = f2bf(v.x * sc + bi);
    hs[n4 * 4 + 1][c] = f2bf(v.y * sc + bi);
    hs[n4 * 4 + 2][c] = f2bf(v.z * sc + bi);
    hs[n4 * 4 + 3][c] = f2bf(v.w * sc + bi);
  }
  __syncthreads();
  int lane = tid & 63, w = tid >> 6;
  int col = lane & 15, quad = lane >> 4;
  int nl = (w & 1) * 16 + col;
  int n = n0 + nl;
  int oh = (w >> 1) * 64;
  bf16x8 hf[4];
  #pragma unroll
  for (int kc = 0; kc < 4; ++kc)
    hf[kc] = *(const bf16x8*)&hs[nl][kc * 32 + quad * 8];
  const ushort* Wq = wB;
  const ushort* Wk = wB + 16384;
  const ushort* Wv = wB + 32768;
  const float scl = 0.12751879752224991f;  // 128^-0.5 * log2(e)
  #pragma unroll
  for (int ot = 0; ot < 4; ++ot) {
    int o0 = oh + ot * 16;
    floatx4 aq = (floatx4)0.f, ak = (floatx4)0.f, av = (floatx4)0.f;
    #pragma unroll
    for (int kc = 0; kc < 4; ++kc) {
      int wo = (o0 + col) * C_ + kc * 32 + quad * 8;
      aq = __builtin_amdgcn_mfma_f32_16x16x32_bf16(*(const bf16x8*)&Wq[wo], hf[kc], aq, 0, 0, 0);
      ak = __builtin_amdgcn_mfma_f32_16x16x32_bf16(*(const bf16x8*)&Wk[wo], hf[kc], ak, 0, 0, 0);
      av = __builtin_amdgcn_mfma_f32_16x16x32_bf16(*(const bf16x8*)&Wv[wo], hf[kc], av, 0, 0, 0);
    }
    float4 bqv = *(const float4*)&bq[o0 + quad * 4];
    float4 bkv = *(const float4*)&bk[o0 + quad * 4];
    float4 bvv = *(const float4*)&bv[o0 + quad * 4];
    uint2 qs = { pkbf((aq[1] + bqv.y) * scl, (aq[0] + bqv.x) * scl),
                 pkbf((aq[3] + bqv.w) * scl, (aq[2] + bqv.z) * scl) };
    uint2 ks = { pkbf(ak[1] + bkv.y, ak[0] + bkv.x),
                 pkbf(ak[3] + bkv.w, ak[2] + bkv.z) };
    *(uint2*)(qT + ((size_t)b * N_ + n) * C_ + o0 + quad * 4) = qs;
    *(uint2*)(kT + ((size_t)b * N_ + n) * C_ + o0 + quad * 4) = ks;
    float vv[4] = {av[0] + bvv.x, av[1] + bvv.y, av[2] + bvv.z, av[3] + bvv.w};
    #pragma unroll
    for (int r = 0; r < 4; ++r)
      vB[((size_t)b * C_ + o0 + quad * 4 + r) * N_ + n] = f2bf(vv[r]);
  }
}

// ---------------- MFMA flash attention: dbuf global_load_lds staging ----------------
// grid 512: sp=bx&3, qblk=(bx>>2)&31, b=bx>>7.  256 thr = 4 waves x 32 q-rows
__global__ __launch_bounds__(256, 3) void attn_kernel(
    const ushort* __restrict__ qT, const ushort* __restrict__ kT,
    const ushort* __restrict__ vB, ushort* __restrict__ Op,
    float* __restrict__ Mv, float* __restrict__ Lv) {
  __shared__ __align__(16) ushort Ks[2][MT * 128];   // 2 x 8 KB, packed (swizzled chunks)
  __shared__ __align__(16) ushort Vs[2][C_ * MT];    // 2 x 8 KB, packed
  __shared__ __align__(16) ushort Ps[128 * PLD];     // 10 KB
  int sp = blockIdx.x & 3;
  int qblk = (blockIdx.x >> 2) & 31;
  int b = blockIdx.x >> 7;
  int n0 = qblk * 128;
  int tid = threadIdx.x, lane = tid & 63, w = tid >> 6;
  int col = lane & 15, quad = lane >> 4;
  int wu = __builtin_amdgcn_readfirstlane(w);
  const ushort* kTb = kT + (size_t)b * N_ * C_;
  const ushort* vBb = vB + (size_t)b * C_ * N_;

  bf16x8 qf[2][4];   // Q B-frags for this wave's 32 q-rows (direct from global)
  #pragma unroll
  for (int qt = 0; qt < 2; ++qt)
    #pragma unroll
    for (int kc = 0; kc < 4; ++kc)
      qf[qt][kc] = *(const bf16x8*)(qT + ((size_t)b * N_ + n0 + w * 32 + qt * 16 + col) * C_ + kc * 32 + quad * 8);

  floatx4 Oacc[2][8];
  #pragma unroll
  for (int qt = 0; qt < 2; ++qt)
    #pragma unroll
    for (int ct = 0; ct < 8; ++ct) Oacc[qt][ct] = (floatx4)0.f;
  float mrun[2] = {-1e30f, -1e30f}, lrun[2] = {0.f, 0.f};

  // ---- staging lambda-ish macro: K rows chunk-swizzled on the GLOBAL address ----
  // K: 32 rows x 256B contiguous at kTb + m0*128. LDS pos p of row r holds chunk p^(r&7).
  // V: 128 c-rows x 64B strided; no swizzle needed (floor already).
  #define STAGE(m0v, buf)                                                              \
    {                                                                                  \
      _Pragma("unroll")                                                                \
      for (int j = 0; j < 2; ++j) {                                                    \
        int inst = wu * 2 + j;                                                         \
        int r = inst * 4 + (lane >> 4);                                                \
        int pos = (lane & 15) ^ (r & 7);                                               \
        gl2lds16(kTb + (size_t)((m0v) + r) * 128 + pos * 8, &Ks[buf][inst * 512]);     \
      }                                                                                \
      _Pragma("unroll")                                                                \
      for (int j = 0; j < 2; ++j) {                                                    \
        int inst = wu * 2 + j;                                                         \
        int c = inst * 16 + (lane >> 2);                                               \
        gl2lds16(vBb + (size_t)c * N_ + (m0v) + (lane & 3) * 8, &Vs[buf][inst * 512]); \
      }                                                                                \
    }

  STAGE(sp * 1024, 0);
  __syncthreads();

  for (int it = 0; it < 1024 / MT; ++it) {
    if (it < 1024 / MT - 1) STAGE(sp * 1024 + (it + 1) * MT, (it + 1) & 1);
    const ushort* KsB = Ks[it & 1];
    const ushort* VsB = Vs[it & 1];

    // S^T = K·Q^T per 16-m tile (rows m in-register, cols q)
    floatx4 st[2][2];
    #pragma unroll
    for (int mt = 0; mt < 2; ++mt) {
      int row = mt * 16 + col;
      bf16x8 kf[4];
      #pragma unroll
      for (int kc = 0; kc < 4; ++kc)
        kf[kc] = *(const bf16x8*)&KsB[row * 128 + (((4 * kc + quad) ^ (col & 7)) * 8)];
      #pragma unroll
      for (int qt = 0; qt < 2; ++qt) {
        floatx4 acc = (floatx4)0.f;
        #pragma unroll
        for (int kc = 0; kc < 4; ++kc)
          acc = __builtin_amdgcn_mfma_f32_16x16x32_bf16(kf[kc], qf[qt][kc], acc, 0, 0, 0);
        st[qt][mt] = acc;
      }
    }
    // online softmax: lane owns q = w*32 + qt*16 + col; holds m = mt*16+quad*4+r
    #pragma unroll
    for (int qt = 0; qt < 2; ++qt) {
      float mx = st[qt][0][0];
      #pragma unroll
      for (int mt = 0; mt < 2; ++mt)
        #pragma unroll
        for (int r = 0; r < 4; ++r) mx = fmaxf(mx, st[qt][mt][r]);
      mx = fmaxf(mx, __shfl_xor(mx, 16, 64));
      mx = fmaxf(mx, __shfl_xor(mx, 32, 64));
      float mnew = fmaxf(mrun[qt], mx);
      float al = exp2f(mrun[qt] - mnew);
      mrun[qt] = mnew;
      float lsum = 0.f;
      int prow = (w * 32 + qt * 16 + col) * PLD;
      #pragma unroll
      for (int mt = 0; mt < 2; ++mt) {
        float p0 = exp2f(st[qt][mt][0] - mnew);
        float p1 = exp2f(st[qt][mt][1] - mnew);
        float p2 = exp2f(st[qt][mt][2] - mnew);
        float p3 = exp2f(st[qt][mt][3] - mnew);
        lsum += (p0 + p1) + (p2 + p3);
        uint2 pk = { pkbf(p1, p0), pkbf(p3, p2) };
        *(uint2*)&Ps[prow + mt * 16 + quad * 4] = pk;
      }
      lsum += __shfl_xor(lsum, 16, 64);
      lsum += __shfl_xor(lsum, 32, 64);
      lrun[qt] = lrun[qt] * al + lsum;
      // rescale O: lane's acc rows are q = qt*16 + quad*4 + r -> alpha from lane col'=quad*4+r
      float ar[4];
      #pragma unroll
      for (int r = 0; r < 4; ++r) ar[r] = __shfl(al, quad * 4 + r, 16);
      #pragma unroll
      for (int ct = 0; ct < 8; ++ct) {
        Oacc[qt][ct][0] *= ar[0]; Oacc[qt][ct][1] *= ar[1];
        Oacc[qt][ct][2] *= ar[2]; Oacc[qt][ct][3] *= ar[3];
      }
    }
    // PV: A = P[q][m] (own rows via LDS), B = V[c][m]
    bf16x8 pf[2];
    #pragma unroll
    for (int qt = 0; qt < 2; ++qt)
      pf[qt] = *(const bf16x8*)&Ps[(w * 32 + qt * 16 + col) * PLD + quad * 8];
    #pragma unroll
    for (int ct = 0; ct < 8; ++ct) {
      bf16x8 vf = *(const bf16x8*)&VsB[(ct * 16 + col) * MT + quad * 8];
      #pragma unroll
      for (int qt = 0; qt < 2; ++qt)
        Oacc[qt][ct] = __builtin_amdgcn_mfma_f32_16x16x32_bf16(pf[qt], vf, Oacc[qt][ct], 0, 0, 0);
    }
    __syncthreads();   // single barrier: drains prefetch (had full compute to land) + gates buf reuse
  }

  // epilogue: Op[sp][b][n][c] bf16 (unnormalized) + m,l
  ushort* OpB = Op + (((size_t)sp * B_ + b) * N_ + n0 + w * 32) * C_;
  #pragma unroll
  for (int qt = 0; qt < 2; ++qt)
    #pragma unroll
    for (int ct = 0; ct < 8; ++ct)
      #pragma unroll
      for (int r = 0; r < 4; ++r)
        OpB[(size_t)(qt * 16 + quad * 4 + r) * C_ + ct * 16 + col] = f2bf(Oacc[qt][ct][r]);
  if (quad == 0) {
    #pragma unroll
    for (int qt = 0; qt < 2; ++qt) {
      int idx = b * N_ + n0 + w * 32 + qt * 16 + col;
      Mv[(size_t)sp * (B_ * N_) + idx] = mrun[qt];
      Lv[(size_t)sp * (B_ * N_) + idx] = lrun[qt];
    }
  }
}

// ---------------- fused merge(4 splits) + proj MFMA + residual ----------------
__global__ __launch_bounds__(256) void mergeproj_kernel(
    const ushort* __restrict__ Op, const float* __restrict__ Mv,
    const float* __restrict__ Lv, const ushort* __restrict__ wpB,
    const float* __restrict__ bp, const float* __restrict__ x,
    float* __restrict__ out) {
  int tid = threadIdx.x, lane = tid & 63, w = tid >> 6;
  int col = lane & 15, quad = lane >> 4;
  int b = blockIdx.x >> 7;
  int n = (blockIdx.x & 127) * 32 + (w & 1) * 16 + col;
  int oh = (w >> 1) * 64;
  int nIdx = b * N_ + n;
  float m[NSPLIT], l[NSPLIT];
  #pragma unroll
  for (int sp = 0; sp < NSPLIT; ++sp) {
    m[sp] = Mv[sp * (B_ * N_) + nIdx];
    l[sp] = Lv[sp * (B_ * N_) + nIdx];
  }
  float M = fmaxf(fmaxf(m[0], m[1]), fmaxf(m[2], m[3]));
  float wg[NSPLIT], den = 0.f;
  #pragma unroll
  for (int sp = 0; sp < NSPLIT; ++sp) { wg[sp] = exp2f(m[sp] - M); den += wg[sp] * l[sp]; }
  float inv = 1.f / den;
  bf16x8 hf[4];
  #pragma unroll
  for (int kc = 0; kc < 4; ++kc) {
    float o[8];
    #pragma unroll
    for (int j = 0; j < 8; ++j) o[j] = 0.f;
    #pragma unroll
    for (int sp = 0; sp < NSPLIT; ++sp) {
      uint4 d = *(const uint4*)&Op[((size_t)sp * (B_ * N_) + nIdx) * C_ + kc * 32 + quad * 8];
      unsigned dd[4] = {d.x, d.y, d.z, d.w};
      #pragma unroll
      for (int j = 0; j < 4; ++j) {
        o[j * 2]     += wg[sp] * bf2f((ushort)(dd[j] & 0xFFFF));
        o[j * 2 + 1] += wg[sp] * bf2f((ushort)(dd[j] >> 16));
      }
    }
    union HF { unsigned u[4]; bf16x8 s; } hfu;
    #pragma unroll
    for (int j = 0; j < 4; ++j)
      hfu.u[j] = pkbf(o[j * 2 + 1] * inv, o[j * 2] * inv);
    hf[kc] = hfu.s;
  }
  #pragma unroll
  for (int ot = 0; ot < 4; ++ot) {
    int o0 = oh + ot * 16;
    floatx4 acc = (floatx4)0.f;
    #pragma unroll
    for (int kc = 0; kc < 4; ++kc) {
      int wo = (o0 + col) * C_ + kc * 32 + quad * 8;
      acc = __builtin_amdgcn_mfma_f32_16x16x32_bf16(*(const bf16x8*)&wpB[wo], hf[kc], acc, 0, 0, 0);
    }
    float4 bpv = *(const float4*)&bp[o0 + quad * 4];
    float bb[4] = {bpv.x, bpv.y, bpv.z, bpv.w};
    #pragma unroll
    for (int r = 0; r < 4; ++r) {
      size_t idx = ((size_t)b * C_ + o0 + quad * 4 + r) * N_ + n;
      out[idx] = acc[r] + bb[r] + x[idx];
    }
  }
}

extern "C" void kernel_launch(void* const* d_in, const int* in_sizes, int n_in,
                              void* d_out, int out_size, void* d_ws, size_t ws_size,
                              hipStream_t stream) {
  const float* x        = (const float*)d_in[0];
  const float* gn_scale = (const float*)d_in[1];
  const float* gn_bias  = (const float*)d_in[2];
  const float* wq = (const float*)d_in[3];
  const float* bq = (const float*)d_in[4];
  const float* wk = (const float*)d_in[5];
  const float* bk = (const float*)d_in[6];
  const float* wv = (const float*)d_in[7];
  const float* bv = (const float*)d_in[8];
  const float* wp = (const float*)d_in[9];
  const float* bp = (const float*)d_in[10];
  float* out = (float*)d_out;

  // workspace map (32 MB):
  // [0,256K) Mv | [256K,512K) Lv | [512K,640K) wB (4x32KB bf16) | [640K,+2KB) gstat
  // [4M,8M) qT | [8M,12M) kT | [12M,16M) vB | [16M,32M) Op[4][B][N][C] bf16
  char* ws = (char*)d_ws;
  float*  Mv    = (float*)ws;
  float*  Lv    = (float*)(ws + 262144);
  ushort* wB    = (ushort*)(ws + 524288);
  float*  gstat = (float*)(ws + 655360);
  ushort* qT    = (ushort*)(ws + (4u << 20));
  ushort* kT    = (ushort*)(ws + (8u << 20));
  ushort* vB    = (ushort*)(ws + (12u << 20));
  ushort* Op    = (ushort*)(ws + (16u << 20));
  ushort* wpB   = wB + 49152;

  prep_kernel<<<512, 256, 0, stream>>>(x, gstat, wq, wk, wv, wp, wB);
  gnqkv_kernel<<<512, 256, 0, stream>>>(x, gstat, gn_scale, gn_bias, wB, bq, bk, bv, qT, kT, vB);
  attn_kernel<<<512, 256, 0, stream>>>(qT, kT, vB, Op, Mv, Lv);
  mergeproj_kernel<<<512, 256, 0, stream>>>(Op, Mv, Lv, wpB, bp, x, out);
}